// Round 18
// baseline (1196.189 us; speedup 1.0000x reference)
//
#include <hip/hip_runtime.h>

// ---------------- problem constants ----------------
#define B_    32
#define S_    729
#define E_    1152
#define H_    16
#define D_    72
#define M1_   23328      // B_*S_
#define MPAD_ 23424      // 183*128
#define SQ_   768        // Q rows padded (12*64)
#define SK_   768        // K rows padded (6*128)
#define DP_   96         // head dim padded
#define VR_   96         // V^T rows (d padded)
#define SCALE_ 0.11785113019775793f  // 72^-0.5

typedef __attribute__((ext_vector_type(8))) _Float16 f16x8;
typedef __attribute__((ext_vector_type(4))) _Float16 f16x4;
typedef __attribute__((ext_vector_type(4))) float    f32x4;

#define GLDS16(g, l) __builtin_amdgcn_global_load_lds(                      \
    (__attribute__((address_space(1))) void*)(g),                           \
    (__attribute__((address_space(3))) void*)(l), 16, 0, 0)

union H2U { _Float16 h[2]; uint32_t u; };

// ------- fp32 -> fp16 convert (3 tensors) + targeted pad zeroing --------
#define N4H  6718464   // (M1_*E_)/4
#define N4W1 995328    // (3456*1152)/4
#define N4W2 331776    // (1152*1152)/4
#define NQC  (512 * 768 * 3)   // Qp pad chunks (16B each)
#define NKC  (512 * 768 * 3)   // Kp pad chunks
#define NVR  (512 * 72)        // Vtp pad rows (39 shorts each)
__global__ void cvt_all(const float* __restrict__ hid, const float* __restrict__ w1,
                        const float* __restrict__ w2, _Float16* __restrict__ o1,
                        _Float16* __restrict__ o2, _Float16* __restrict__ o3,
                        _Float16* __restrict__ Qp, _Float16* __restrict__ Kp,
                        _Float16* __restrict__ Vtp) {
  const int stride = gridDim.x * blockDim.x;
  const int tid0 = blockIdx.x * blockDim.x + threadIdx.x;
  const uint4 z4 = make_uint4(0, 0, 0, 0);
  for (int idx = tid0; idx < NQC; idx += stride) {
    int row = idx / 3, c = idx - row * 3;
    *(uint4*)((char*)Qp + (size_t)row * 192 + 144 + c * 16) = z4;
  }
  for (int idx = tid0; idx < NKC; idx += stride) {
    int row = idx / 3, c = idx - row * 3;
    *(uint4*)((char*)Kp + (size_t)row * 192 + 144 + c * 16) = z4;
  }
  for (int idx = tid0; idx < NVR; idx += stride) {
    _Float16* p = Vtp + (size_t)idx * 768 + 729;
    #pragma unroll
    for (int s = 0; s < 39; ++s) p[s] = (_Float16)0.0f;
  }
  for (int i = tid0; i < N4H + N4W1 + N4W2; i += stride) {
    const float* s; _Float16* d; int j;
    if (i < N4H)             { s = hid; d = o1; j = i; }
    else if (i < N4H + N4W1) { s = w1;  d = o2; j = i - N4H; }
    else                     { s = w2;  d = o3; j = i - N4H - N4W1; }
    f32x4 v = __builtin_nontemporal_load((const f32x4*)(s + (size_t)j * 4));
    f16x4 o;
    o[0] = (_Float16)v[0]; o[1] = (_Float16)v[1];
    o[2] = (_Float16)v[2]; o[3] = (_Float16)v[3];
    __builtin_nontemporal_store(o, (f16x4*)(d + (size_t)j * 4));
  }
}

// ---------------- 128x128 fp16 MFMA GEMM (m97 structure) ----------------
template<int MODE>
__global__ __launch_bounds__(256)
void gemm_f16(const _Float16* __restrict__ A, const _Float16* __restrict__ W,
              const float* __restrict__ bias,
              _Float16* __restrict__ Qp, _Float16* __restrict__ Kp,
              _Float16* __restrict__ Vtp, float* __restrict__ Cout)
{
  int mb, nb;
  if (MODE == 0) {
    const int xcd  = blockIdx.x & 7;
    const int slot = blockIdx.x >> 3;
    const int st   = slot >> 4;
    const int w    = slot & 15;
    const int stm  = st % 6, stn = st / 6;
    const int mloc = stm * 4 + (w & 3);
    nb = stn * 4 + (w >> 2);
    const int stripe = (xcd < 7) ? 23 : 22;
    if (mloc >= stripe || nb >= 27) return;
    mb = (xcd < 7 ? xcd * 23 : 161) + mloc;
  } else {
    mb = blockIdx.x; nb = blockIdx.y;
  }

  __shared__ _Float16 As[128 * 64];
  __shared__ _Float16 Bs[128 * 64];
  const int tid = threadIdx.x;
  const int l  = tid & 63;
  const int wv = tid >> 6;
  const int lq = l & 15, lk = l >> 4;
  const int m0 = mb * 128;
  const int n0 = nb * 128;
  const int wm = (wv & 1) * 64, wn = (wv >> 1) * 64;
  const int srow = l >> 3;
  const int scol = (l & 7) * 8;

  f32x4 acc[4][4] = {};

  for (int k0 = 0; k0 < 1152; k0 += 64) {
    #pragma unroll
    for (int q = 0; q < 4; ++q) {
      int chunk = wv * 4 + q;
      int row = chunk * 8 + srow;
      GLDS16(A + (size_t)(m0 + row) * 1152 + k0 + scol, &As[chunk * 512 + l * 8]);
      GLDS16(W + (size_t)(n0 + row) * 1152 + k0 + scol, &Bs[chunk * 512 + l * 8]);
    }
    __syncthreads();
    #pragma unroll
    for (int kk = 0; kk < 64; kk += 32) {
      f16x8 a[4], b[4];
      #pragma unroll
      for (int i = 0; i < 4; ++i)
        a[i] = *(const f16x8*)&As[(wm + 16 * i + lq) * 64 + kk + lk * 8];
      #pragma unroll
      for (int j = 0; j < 4; ++j)
        b[j] = *(const f16x8*)&Bs[(wn + 16 * j + lq) * 64 + kk + lk * 8];
      #pragma unroll
      for (int i = 0; i < 4; ++i)
        #pragma unroll
        for (int j = 0; j < 4; ++j)
          acc[i][j] = __builtin_amdgcn_mfma_f32_16x16x32_f16(a[i], b[j], acc[i][j], 0, 0, 0);
    }
    __syncthreads();
  }

  #pragma unroll
  for (int i = 0; i < 4; ++i) {
    #pragma unroll
    for (int j = 0; j < 4; ++j) {
      int n = n0 + wn + 16 * j + lq;
      float bn = bias[n];
      #pragma unroll
      for (int r = 0; r < 4; ++r) {
        int m = m0 + wm + 16 * i + lk * 4 + r;
        if (m >= M1_) continue;
        float v = acc[i][j][r] + bn;
        if (MODE == 0) {
          unsigned um = (unsigned)m;
          unsigned bq = um / 729u, s = um - bq * 729u;
          unsigned un = (unsigned)n;
          unsigned which = un / 1152u, e = un - which * 1152u;
          unsigned h = e / 72u, d = e - h * 72u;
          unsigned bh = bq * 16u + h;
          if (which == 0) {
            Qp[((size_t)bh * SQ_ + s) * DP_ + d] = (_Float16)(v * SCALE_);
          } else if (which == 1) {
            Kp[((size_t)bh * SK_ + s) * DP_ + d] = (_Float16)v;
          } else {
            Vtp[((size_t)bh * VR_ + d) * 768 + s] = (_Float16)v;
          }
        } else {
          Cout[(size_t)m * 1152 + n] = v;
        }
      }
    }
  }
}

// ---------------- fused attention v18: QBLK=64 ----------------
// 512 thr (8 waves = 4 q-groups x 2 k-slices); one (bh, 64-q tile).
// XCD-pinned. Same 12-tile counted-vmcnt pipeline, exchange, NT sweep as
// v13 — only index maps changed. Halves K/V staging traffic per q-row.
struct AttnSmem {
  union {
    char     stage[2][24576];    // K tile [128][192B] / V tile [96][256B]
    float    ored[2][64][96];    // 48KB O-reduce (after PV)
    _Float16 p16[32][768];       // 48KB P spill (two 32-row passes)
  };
  uint32_t pexch[8][64][4];      // per-wave P exchange, 8KB
  float redmax[64][2];
  float redsum[64][2];
  float invl[64];
};

__global__ __launch_bounds__(512, 4)
void attn_k(const _Float16* __restrict__ Q, const _Float16* __restrict__ K,
            const _Float16* __restrict__ Vt, float* __restrict__ scores,
            _Float16* __restrict__ AO)
{
  __shared__ AttnSmem sm;
  const int tid = threadIdx.x;
  const int l   = tid & 63;
  const int wv  = tid >> 6;
  const int lq  = l & 15, lk = l >> 4;
  const int i   = wv >> 1;         // q-group 0..3 (rows 16i..16i+15)
  const int sl  = wv & 1;          // k-slice 0..1
  const int p    = blockIdx.x;
  const int xcd  = p & 7;
  const int slot = p >> 3;
  const int hl   = slot / 12;
  const int qt   = slot - hl * 12;
  const int bh   = hl * 8 + xcd;
  const int q0   = qt * 64;
  const int b    = bh >> 4, h = bh & 15;

  const _Float16* Qb = Q  + (size_t)bh * SQ_ * DP_;
  const _Float16* Kb = K  + (size_t)bh * SK_ * DP_;
  const _Float16* Vb = Vt + (size_t)bh * VR_ * 768;

  auto stage = [&](int idx) {
    char* buf = sm.stage[idx & 1];
    if (idx < 6) {
      #pragma unroll
      for (int it = 0; it < 3; ++it) {
        int s = it * 512 + tid;
        int row = s / 12, cp = s - row * 12;
        int cc = (cp < 8) ? (cp ^ (row & 7)) : (8 + ((cp & 3) ^ ((row >> 1) & 3)));
        GLDS16(Kb + (size_t)(idx * 128 + row) * DP_ + cc * 8, buf + s * 16);
      }
    } else {
      #pragma unroll
      for (int it = 0; it < 3; ++it) {
        int s = it * 512 + tid;
        int row = s >> 4, cp = s & 15;
        int cc = cp ^ (row & 15);
        GLDS16(Vb + (size_t)row * 768 + (idx - 6) * 128 + cc * 8, buf + s * 16);
      }
    }
  };

  // ---- prologue ----
  stage(0);
  stage(1);
  f16x8 aq[3];
  {
    const _Float16* qp = Qb + (size_t)(q0 + 16 * i + lq) * DP_ + lk * 8;
    aq[0] = *(const f16x8*)(qp);
    aq[1] = *(const f16x8*)(qp + 32);
    aq[2] = *(const f16x8*)(qp + 64);
  }
  asm volatile("s_waitcnt vmcnt(0)" ::: "memory");
  __builtin_amdgcn_s_barrier();

  // ---- QK^T over 6 staged K-tiles; c in 0..23, cb=4(c>>1)+2sl+(c&1) ----
  f32x4 sacc[24] = {};
  #pragma unroll
  for (int t = 0; t < 6; ++t) {
    asm volatile("s_waitcnt vmcnt(3)" ::: "memory");
    __builtin_amdgcn_s_barrier();
    const char* bufp = sm.stage[t & 1];
    #pragma unroll
    for (int j = 0; j < 4; ++j) {
      int c = 4 * t + j;
      int lcb = 4 * (j >> 1) + 2 * sl + (j & 1);  // 0..7 within tile
      int row = lcb * 16 + lq;
      #pragma unroll
      for (int t3 = 0; t3 < 3; ++t3) {
        int cc = 4 * t3 + lk;
        int cp = (cc < 8) ? (cc ^ (row & 7)) : (8 + ((cc & 3) ^ ((row >> 1) & 3)));
        f16x8 ka = *(const f16x8*)(bufp + row * 192 + cp * 16);
        sacc[c] = __builtin_amdgcn_mfma_f32_16x16x32_f16(ka, aq[t3], sacc[c], 0, 0, 0);
      }
    }
    asm volatile("s_waitcnt lgkmcnt(0)" ::: "memory");
    __builtin_amdgcn_s_barrier();
    stage(t + 2);                 // K2..K5 then V0,V1
  }

  // ---- mask invalid k ----
  if (sl == 0) {
    // c=23 -> cb=45, k = 720+4lk+r
    #pragma unroll
    for (int r = 0; r < 4; ++r)
      if (720 + 4 * lk + r > 728) sacc[23][r] = -1e30f;
  } else {
    // c=22 -> cb=46, c=23 -> cb=47: fully invalid
    #pragma unroll
    for (int r = 0; r < 4; ++r) { sacc[22][r] = -1e30f; sacc[23][r] = -1e30f; }
  }

  // ---- row max ----
  float m = -1e30f;
  #pragma unroll
  for (int c = 0; c < 24; ++c)
    #pragma unroll
    for (int r = 0; r < 4; ++r) m = fmaxf(m, sacc[c][r]);
  m = fmaxf(m, __shfl_xor(m, 16));
  m = fmaxf(m, __shfl_xor(m, 32));
  if (lk == 0) sm.redmax[16 * i + lq][sl] = m;
  asm volatile("s_waitcnt lgkmcnt(0)" ::: "memory");
  __builtin_amdgcn_s_barrier();
  float gm;
  { const float* rp = sm.redmax[16 * i + lq];
    gm = fmaxf(rp[0], rp[1]); }

  // ---- exp + row sum ----
  float sum = 0.f;
  #pragma unroll
  for (int c = 0; c < 24; ++c)
    #pragma unroll
    for (int r = 0; r < 4; ++r) {
      float e = __expf(sacc[c][r] - gm);
      sacc[c][r] = e;
      sum += e;
    }
  sum += __shfl_xor(sum, 16);
  sum += __shfl_xor(sum, 32);
  if (lk == 0) sm.redsum[16 * i + lq][sl] = sum;
  asm volatile("s_waitcnt lgkmcnt(0)" ::: "memory");
  __builtin_amdgcn_s_barrier();
  float inv;
  { const float* rp = sm.redsum[16 * i + lq];
    inv = 1.0f / (rp[0] + rp[1]); }
  if (lk == 0 && sl == 0) sm.invl[16 * i + lq] = inv;

  // ---- pack P to fp16 pairs; sacc dead after ----
  uint32_t pk[24][2];
  #pragma unroll
  for (int c = 0; c < 24; ++c) {
    H2U a0, a1;
    a0.h[0] = (_Float16)sacc[c][0]; a0.h[1] = (_Float16)sacc[c][1];
    a1.h[0] = (_Float16)sacc[c][2]; a1.h[1] = (_Float16)sacc[c][3];
    pk[c][0] = a0.u; pk[c][1] = a1.u;
  }

  // ---- PV over 6 staged V-tiles; two exchanges per tile ----
  f32x4 oacc[6] = {};
  const int srcA = lq + 16 * (2 * (lk & 1));
  const int srcB = srcA + 16;
  #pragma unroll
  for (int v = 0; v < 6; ++v) {
    if (v < 5) { asm volatile("s_waitcnt vmcnt(3)" ::: "memory"); }
    else       { asm volatile("s_waitcnt vmcnt(0)" ::: "memory"); }
    __builtin_amdgcn_s_barrier();
    // exchange u=0: pk[4v], pk[4v+1] (cb pair -> local octets 4sl..4sl+3)
    f16x8 pa0, pa1;
    {
      uint4 w = make_uint4(pk[4 * v][0], pk[4 * v][1], pk[4 * v + 1][0], pk[4 * v + 1][1]);
      *(uint4*)&sm.pexch[wv][l][0] = w;
      asm volatile("s_waitcnt lgkmcnt(0)" ::: "memory");
      __builtin_amdgcn_sched_barrier(0);
      uint2 dA = *(const uint2*)((const char*)&sm.pexch[wv][srcA][0] + (lk >> 1) * 8);
      uint2 dB = *(const uint2*)((const char*)&sm.pexch[wv][srcB][0] + (lk >> 1) * 8);
      pa0 = __builtin_bit_cast(f16x8, make_uint4(dA.x, dA.y, dB.x, dB.y));
    }
    asm volatile("s_waitcnt lgkmcnt(0)" ::: "memory");
    __builtin_amdgcn_sched_barrier(0);
    // exchange u=1: pk[4v+2], pk[4v+3] (local octets 8+4sl..)
    {
      uint4 w = make_uint4(pk[4 * v + 2][0], pk[4 * v + 2][1], pk[4 * v + 3][0], pk[4 * v + 3][1]);
      *(uint4*)&sm.pexch[wv][l][0] = w;
      asm volatile("s_waitcnt lgkmcnt(0)" ::: "memory");
      __builtin_amdgcn_sched_barrier(0);
      uint2 dA = *(const uint2*)((const char*)&sm.pexch[wv][srcA][0] + (lk >> 1) * 8);
      uint2 dB = *(const uint2*)((const char*)&sm.pexch[wv][srcB][0] + (lk >> 1) * 8);
      pa1 = __builtin_bit_cast(f16x8, make_uint4(dA.x, dA.y, dB.x, dB.y));
    }

    const char* bufp = sm.stage[v & 1];
    #pragma unroll
    for (int db = 0; db < 6; ++db) {
      int row = db * 16 + lq;
      int cc0 = 4 * sl + lk;
      int cp0 = cc0 ^ (row & 15);
      f16x8 bv0 = *(const f16x8*)(bufp + row * 256 + cp0 * 16);
      oacc[db] = __builtin_amdgcn_mfma_f32_16x16x32_f16(pa0, bv0, oacc[db], 0, 0, 0);
      int cc1 = 8 + 4 * sl + lk;
      int cp1 = cc1 ^ (row & 15);
      f16x8 bv1 = *(const f16x8*)(bufp + row * 256 + cp1 * 16);
      oacc[db] = __builtin_amdgcn_mfma_f32_16x16x32_f16(pa1, bv1, oacc[db], 0, 0, 0);
    }
    asm volatile("s_waitcnt lgkmcnt(0)" ::: "memory");
    __builtin_amdgcn_s_barrier();
    if (v < 4) stage(v + 8);      // V2..V5
  }

  // ---- cross-slice O reduce ----
  #pragma unroll
  for (int db = 0; db < 6; ++db)
    #pragma unroll
    for (int r = 0; r < 4; ++r) {
      int row = 16 * i + lk * 4 + r;
      sm.ored[sl][row][(db * 16 + lq) ^ (row & 12)] = oacc[db][r];
    }
  asm volatile("s_waitcnt lgkmcnt(0)" ::: "memory");
  __builtin_amdgcn_s_barrier();

  // ---- AO write: 8 threads/row x 9 d-elems ----
  {
    int qq = tid >> 3, dc = tid & 7;
    int qglob = q0 + qq;
    if (qglob < S_) {
      int d0 = dc * 9;
      float iv = sm.invl[qq];
      _Float16* ap = AO + ((size_t)(b * S_ + qglob)) * E_ + h * D_ + d0;
      #pragma unroll
      for (int e = 0; e < 9; ++e) {
        int col = (d0 + e) ^ (qq & 12);
        float v = sm.ored[0][qq][col] + sm.ored[1][qq][col];
        ap[e] = (_Float16)(v * iv);
      }
    }
  }
  asm volatile("s_waitcnt lgkmcnt(0)" ::: "memory");
  __builtin_amdgcn_s_barrier();

  // ---- scores: 2 passes of {P spill (32 rows) + NT wave-per-row sweep} ----
  #pragma unroll
  for (int pass = 0; pass < 2; ++pass) {
    if ((i >> 1) == pass) {
      int lrow = 16 * (i & 1) + lq;          // 0..31 within pass
      char* base = (char*)sm.p16 + lrow * 1536;
      #pragma unroll
      for (int c = 0; c < 24; ++c) {
        int cb = 4 * (c >> 1) + 2 * sl + (c & 1);
        int off = cb * 32 + 8 * lk;
        int swz = off ^ ((lrow & 7) << 4);
        *(uint2*)(base + swz) = make_uint2(pk[c][0], pk[c][1]);
      }
    }
    asm volatile("s_waitcnt lgkmcnt(0)" ::: "memory");
    __builtin_amdgcn_s_barrier();

    #pragma unroll
    for (int rr = 0; rr < 4; ++rr) {
      int lrow = wv * 4 + rr;                // 0..31
      int grow = 32 * pass + lrow;
      int qg   = q0 + grow;
      if (qg < S_) {
        float ivr = sm.invl[grow];
        float* srow = scores + (size_t)bh * S_ * S_ + (size_t)qg * S_;
        const char* base = (const char*)sm.p16 + lrow * 1536;
        #pragma unroll
        for (int u = 0; u < 3; ++u) {
          int off = u * 512 + 8 * l;
          int swz = off ^ ((lrow & 7) << 4);
          f16x4 pv4 = *(const f16x4*)(base + swz);
          int k0 = u * 256 + 4 * l;
          f32x4 vv;
          vv[0] = (float)pv4[0] * ivr; vv[1] = (float)pv4[1] * ivr;
          vv[2] = (float)pv4[2] * ivr; vv[3] = (float)pv4[3] * ivr;
          if (k0 + 3 <= 728)
            __builtin_nontemporal_store(vv, (f32x4*)(srow + k0));
          else if (k0 == 728)
            __builtin_nontemporal_store(vv[0], srow + 728);
        }
      }
    }
    if (pass == 0) {
      asm volatile("s_waitcnt lgkmcnt(0)" ::: "memory");  // sweep reads done
      __builtin_amdgcn_s_barrier();                       // before pass-1 spill
    }
  }
}

// ---------------- host launch ----------------
extern "C" void kernel_launch(void* const* d_in, const int* in_sizes, int n_in,
                              void* d_out, int out_size, void* d_ws, size_t ws_size,
                              hipStream_t stream)
{
  const float* hidden = (const float*)d_in[0];
  const float* qkv_w  = (const float*)d_in[1];
  const float* qkv_b  = (const float*)d_in[2];
  const float* out_w  = (const float*)d_in[3];
  const float* out_b  = (const float*)d_in[4];
  float* out    = (float*)d_out;
  float* scores = out + (size_t)M1_ * E_;

  char* ws = (char*)d_ws;
  const size_t szA1 = (size_t)MPAD_ * 1152 * 2;
  const size_t szWq = (size_t)3456 * 1152 * 2;
  const size_t szWo = (size_t)1152 * 1152 * 2;
  const size_t szQ  = (size_t)512 * SQ_ * DP_ * 2;
  const size_t szK  = (size_t)512 * SK_ * DP_ * 2;
  const size_t szV  = (size_t)512 * VR_ * 768 * 2;
  const size_t offA1 = 0;
  const size_t offWq = offA1 + szA1;
  const size_t offWo = offWq + szWq;
  const size_t offQ  = offWo + szWo;
  const size_t offK  = offQ  + szQ;
  const size_t offVt = offK  + szK;
  const size_t need  = offVt + szV;          // ~278 MiB
  if (ws_size < need) return;

  _Float16* A1  = (_Float16*)(ws + offA1);
  _Float16* Wq  = (_Float16*)(ws + offWq);
  _Float16* Wo  = (_Float16*)(ws + offWo);
  _Float16* Qp  = (_Float16*)(ws + offQ);
  _Float16* Kp  = (_Float16*)(ws + offK);
  _Float16* Vtp = (_Float16*)(ws + offVt);
  _Float16* AO  = A1;   // reuse A1 (dead after GEMM1)

  cvt_all<<<2048, 256, 0, stream>>>(hidden, qkv_w, out_w, A1, Wq, Wo, Qp, Kp, Vtp);

  gemm_f16<0><<<5376, 256, 0, stream>>>(A1, Wq, qkv_b, Qp, Kp, Vtp, nullptr);
  attn_k<<<6144, 512, 0, stream>>>(Qp, Kp, Vtp, scores, AO);
  gemm_f16<1><<<dim3(183, 9), 256, 0, stream>>>(AO, Wo, out_b, nullptr, nullptr, nullptr, out);
}

// Round 19
// 1109.359 us; speedup vs baseline: 1.0783x; 1.0783x over previous
//
#include <hip/hip_runtime.h>

// ---------------- problem constants ----------------
#define B_    32
#define S_    729
#define E_    1152
#define H_    16
#define D_    72
#define M1_   23328      // B_*S_
#define MPAD_ 23424      // 183*128
#define SQ_   736        // Q rows padded (23*32)
#define SK_   768        // K rows padded (6*128)
#define DP_   96         // head dim padded
#define VR_   96         // V^T rows (d padded)
#define SCALE_ 0.11785113019775793f  // 72^-0.5

typedef __attribute__((ext_vector_type(8))) _Float16 f16x8;
typedef __attribute__((ext_vector_type(4))) _Float16 f16x4;
typedef __attribute__((ext_vector_type(4))) float    f32x4;

#define GLDS16(g, l) __builtin_amdgcn_global_load_lds(                      \
    (__attribute__((address_space(1))) void*)(g),                           \
    (__attribute__((address_space(3))) void*)(l), 16, 0, 0)

union H2U { _Float16 h[2]; uint32_t u; };

// ------- fp32 -> fp16 convert (3 tensors) + targeted pad zeroing --------
// Pads that MUST be zero (0*NaN=NaN in MFMA k-sums):
//   Qp d-pad [all 736 rows][72..95]  (QK d-sum; either side NaN survives)
//   Kp d-pad [all 768 rows][72..95]  (QK d-sum)
//   Vtp s-pad [d<72][729..767]       (PV k-sum vs P=0)
// All other garbage regions are row/col-isolated into discarded outputs.
#define N4H  6718464   // (M1_*E_)/4
#define N4W1 995328    // (3456*1152)/4
#define N4W2 331776    // (1152*1152)/4
#define NQC  (512 * 736 * 3)   // Qp pad chunks (16B each)
#define NKC  (512 * 768 * 3)   // Kp pad chunks
#define NVR  (512 * 72)        // Vtp pad rows (39 shorts each)
__global__ void cvt_all(const float* __restrict__ hid, const float* __restrict__ w1,
                        const float* __restrict__ w2, _Float16* __restrict__ o1,
                        _Float16* __restrict__ o2, _Float16* __restrict__ o3,
                        _Float16* __restrict__ Qp, _Float16* __restrict__ Kp,
                        _Float16* __restrict__ Vtp) {
  const int stride = gridDim.x * blockDim.x;
  const int tid0 = blockIdx.x * blockDim.x + threadIdx.x;
  const uint4 z4 = make_uint4(0, 0, 0, 0);
  // pad zeroing (small)
  for (int idx = tid0; idx < NQC; idx += stride) {
    int row = idx / 3, c = idx - row * 3;
    *(uint4*)((char*)Qp + (size_t)row * 192 + 144 + c * 16) = z4;
  }
  for (int idx = tid0; idx < NKC; idx += stride) {
    int row = idx / 3, c = idx - row * 3;
    *(uint4*)((char*)Kp + (size_t)row * 192 + 144 + c * 16) = z4;
  }
  for (int idx = tid0; idx < NVR; idx += stride) {
    _Float16* p = Vtp + (size_t)idx * 768 + 729;
    #pragma unroll
    for (int s = 0; s < 39; ++s) p[s] = (_Float16)0.0f;
  }
  // fp32 -> fp16 streams (read-once/write-once: non-temporal, ext-vector types)
  for (int i = tid0; i < N4H + N4W1 + N4W2; i += stride) {
    const float* s; _Float16* d; int j;
    if (i < N4H)             { s = hid; d = o1; j = i; }
    else if (i < N4H + N4W1) { s = w1;  d = o2; j = i - N4H; }
    else                     { s = w2;  d = o3; j = i - N4H - N4W1; }
    f32x4 v = __builtin_nontemporal_load((const f32x4*)(s + (size_t)j * 4));
    f16x4 o;
    o[0] = (_Float16)v[0]; o[1] = (_Float16)v[1];
    o[2] = (_Float16)v[2]; o[3] = (_Float16)v[3];
    __builtin_nontemporal_store(o, (f16x4*)(d + (size_t)j * 4));
  }
}

// ---------------- 128x128 fp16 MFMA GEMM (m97 structure) ----------------
// MODE 0: XCD-slab remap (neutral but harmless; bijection verified).
template<int MODE>
__global__ __launch_bounds__(256)
void gemm_f16(const _Float16* __restrict__ A, const _Float16* __restrict__ W,
              const float* __restrict__ bias,
              _Float16* __restrict__ Qp, _Float16* __restrict__ Kp,
              _Float16* __restrict__ Vtp, float* __restrict__ Cout)
{
  int mb, nb;
  if (MODE == 0) {
    const int xcd  = blockIdx.x & 7;
    const int slot = blockIdx.x >> 3;      // 0..671
    const int st   = slot >> 4;            // 0..41
    const int w    = slot & 15;
    const int stm  = st % 6, stn = st / 6; // 6 m-supertiles x 7 n-supertiles
    const int mloc = stm * 4 + (w & 3);
    nb = stn * 4 + (w >> 2);
    const int stripe = (xcd < 7) ? 23 : 22;
    if (mloc >= stripe || nb >= 27) return;   // block-uniform early-out
    mb = (xcd < 7 ? xcd * 23 : 161) + mloc;
  } else {
    mb = blockIdx.x; nb = blockIdx.y;
  }

  __shared__ _Float16 As[128 * 64];
  __shared__ _Float16 Bs[128 * 64];
  const int tid = threadIdx.x;
  const int l  = tid & 63;
  const int wv = tid >> 6;
  const int lq = l & 15, lk = l >> 4;
  const int m0 = mb * 128;
  const int n0 = nb * 128;
  const int wm = (wv & 1) * 64, wn = (wv >> 1) * 64;
  const int srow = l >> 3;
  const int scol = (l & 7) * 8;

  f32x4 acc[4][4] = {};

  for (int k0 = 0; k0 < 1152; k0 += 64) {
    #pragma unroll
    for (int q = 0; q < 4; ++q) {
      int chunk = wv * 4 + q;
      int row = chunk * 8 + srow;
      GLDS16(A + (size_t)(m0 + row) * 1152 + k0 + scol, &As[chunk * 512 + l * 8]);
      GLDS16(W + (size_t)(n0 + row) * 1152 + k0 + scol, &Bs[chunk * 512 + l * 8]);
    }
    __syncthreads();
    #pragma unroll
    for (int kk = 0; kk < 64; kk += 32) {
      f16x8 a[4], b[4];
      #pragma unroll
      for (int i = 0; i < 4; ++i)
        a[i] = *(const f16x8*)&As[(wm + 16 * i + lq) * 64 + kk + lk * 8];
      #pragma unroll
      for (int j = 0; j < 4; ++j)
        b[j] = *(const f16x8*)&Bs[(wn + 16 * j + lq) * 64 + kk + lk * 8];
      #pragma unroll
      for (int i = 0; i < 4; ++i)
        #pragma unroll
        for (int j = 0; j < 4; ++j)
          acc[i][j] = __builtin_amdgcn_mfma_f32_16x16x32_f16(a[i], b[j], acc[i][j], 0, 0, 0);
    }
    __syncthreads();
  }

  #pragma unroll
  for (int i = 0; i < 4; ++i) {
    #pragma unroll
    for (int j = 0; j < 4; ++j) {
      int n = n0 + wn + 16 * j + lq;
      float bn = bias[n];
      #pragma unroll
      for (int r = 0; r < 4; ++r) {
        int m = m0 + wm + 16 * i + lk * 4 + r;
        if (m >= M1_) continue;
        float v = acc[i][j][r] + bn;
        if (MODE == 0) {
          unsigned um = (unsigned)m;
          unsigned bq = um / 729u, s = um - bq * 729u;
          unsigned un = (unsigned)n;
          unsigned which = un / 1152u, e = un - which * 1152u;
          unsigned h = e / 72u, d = e - h * 72u;
          unsigned bh = bq * 16u + h;
          if (which == 0) {
            Qp[((size_t)bh * SQ_ + s) * DP_ + d] = (_Float16)(v * SCALE_);
          } else if (which == 1) {
            Kp[((size_t)bh * SK_ + s) * DP_ + d] = (_Float16)v;
          } else {
            Vtp[((size_t)bh * VR_ + d) * 768 + s] = (_Float16)v;
          }
        } else {
          Cout[(size_t)m * 1152 + n] = v;
        }
      }
    }
  }
}

// ---------------- fused attention (v13/v17, best validated) ----------------
// 512 thr (8 waves); one (bh, 32-q tile). XCD-pinned. 12-tile async pipeline
// (6 K + 6 V), counted vmcnt(3). LDS pexch. NT wave-per-row scores sweep.
struct AttnSmem {
  union {
    char     stage[2][24576];    // K tile [128][192B] / V tile [96][256B]
    float    ored[4][32][96];    // 48KB O-reduce (after PV)
    _Float16 p16[32][768];       // 48KB P spill (after AO write)
  };
  uint32_t pexch[8][64][4];      // per-wave P exchange, 8KB
  float redmax[32][4];
  float redsum[32][4];
  float invl[32];
};

__global__ __launch_bounds__(512, 4)
void attn_k(const _Float16* __restrict__ Q, const _Float16* __restrict__ K,
            const _Float16* __restrict__ Vt, float* __restrict__ scores,
            _Float16* __restrict__ AO)
{
  __shared__ AttnSmem sm;
  const int tid = threadIdx.x;
  const int l   = tid & 63;
  const int wv  = tid >> 6;
  const int lq  = l & 15, lk = l >> 4;
  const int i   = wv >> 2;
  const int sl  = wv & 3;
  // XCD-pinned decode: phys block p -> xcd = p%8; head bh = hl*8+xcd
  const int p    = blockIdx.x;
  const int xcd  = p & 7;
  const int slot = p >> 3;
  const int hl   = slot / 23;
  const int qt   = slot - hl * 23;
  const int bh   = hl * 8 + xcd;
  const int q0   = qt * 32;
  const int b    = bh >> 4, h = bh & 15;

  const _Float16* Qb = Q  + (size_t)bh * SQ_ * DP_;
  const _Float16* Kb = K  + (size_t)bh * SK_ * DP_;
  const _Float16* Vb = Vt + (size_t)bh * VR_ * 768;

  // tiles 0..5 = K tiles, 6..11 = V tiles; buffer = idx&1
  auto stage = [&](int idx) {
    char* buf = sm.stage[idx & 1];
    if (idx < 6) {
      #pragma unroll
      for (int it = 0; it < 3; ++it) {
        int s = it * 512 + tid;                 // 1536 chunks of 16B
        int row = s / 12, cp = s - row * 12;
        int cc = (cp < 8) ? (cp ^ (row & 7)) : (8 + ((cp & 3) ^ ((row >> 1) & 3)));
        GLDS16(Kb + (size_t)(idx * 128 + row) * DP_ + cc * 8, buf + s * 16);
      }
    } else {
      #pragma unroll
      for (int it = 0; it < 3; ++it) {
        int s = it * 512 + tid;
        int row = s >> 4, cp = s & 15;
        int cc = cp ^ (row & 15);
        GLDS16(Vb + (size_t)row * 768 + (idx - 6) * 128 + cc * 8, buf + s * 16);
      }
    }
  };

  // ---- prologue: 2 K-tiles in flight + Q frags ----
  stage(0);
  stage(1);
  f16x8 aq[3];
  {
    const _Float16* qp = Qb + (size_t)(q0 + 16 * i + lq) * DP_ + lk * 8;
    aq[0] = *(const f16x8*)(qp);
    aq[1] = *(const f16x8*)(qp + 32);
    aq[2] = *(const f16x8*)(qp + 64);
  }
  asm volatile("s_waitcnt vmcnt(0)" ::: "memory");
  __builtin_amdgcn_s_barrier();

  // ---- QK^T over 6 staged K-tiles ----
  f32x4 sacc[12] = {};
  #pragma unroll
  for (int t = 0; t < 6; ++t) {
    asm volatile("s_waitcnt vmcnt(3)" ::: "memory");
    __builtin_amdgcn_s_barrier();
    const char* bufp = sm.stage[t & 1];
    #pragma unroll
    for (int lcb = 0; lcb < 2; ++lcb) {
      int row = (2 * sl + lcb) * 16 + lq;
      #pragma unroll
      for (int t3 = 0; t3 < 3; ++t3) {
        int cc = 4 * t3 + lk;
        int cp = (cc < 8) ? (cc ^ (row & 7)) : (8 + ((cc & 3) ^ ((row >> 1) & 3)));
        f16x8 ka = *(const f16x8*)(bufp + row * 192 + cp * 16);
        sacc[2 * t + lcb] = __builtin_amdgcn_mfma_f32_16x16x32_f16(ka, aq[t3], sacc[2 * t + lcb], 0, 0, 0);
      }
    }
    asm volatile("s_waitcnt lgkmcnt(0)" ::: "memory");
    __builtin_amdgcn_s_barrier();
    stage(t + 2);                 // t+2: K2..K5 then V0,V1
  }

  // ---- mask invalid k (cb >= 45 only at c=10,11) ----
  #pragma unroll
  for (int c = 10; c < 12; ++c) {
    int kbase = (40 + 2 * sl + (c & 1)) * 16 + 4 * lk;
    #pragma unroll
    for (int r = 0; r < 4; ++r)
      if (kbase + r > 728) sacc[c][r] = -1e30f;
  }

  // ---- row max (V0/V1 loads in flight underneath) ----
  float m = -1e30f;
  #pragma unroll
  for (int c = 0; c < 12; ++c)
    #pragma unroll
    for (int r = 0; r < 4; ++r) m = fmaxf(m, sacc[c][r]);
  m = fmaxf(m, __shfl_xor(m, 16));
  m = fmaxf(m, __shfl_xor(m, 32));
  if (lk == 0) sm.redmax[16 * i + lq][sl] = m;
  asm volatile("s_waitcnt lgkmcnt(0)" ::: "memory");
  __builtin_amdgcn_s_barrier();
  float gm;
  { const float* rp = sm.redmax[16 * i + lq];
    gm = fmaxf(fmaxf(rp[0], rp[1]), fmaxf(rp[2], rp[3])); }

  // ---- exp + row sum ----
  float sum = 0.f;
  #pragma unroll
  for (int c = 0; c < 12; ++c)
    #pragma unroll
    for (int r = 0; r < 4; ++r) {
      float e = __expf(sacc[c][r] - gm);
      sacc[c][r] = e;
      sum += e;
    }
  sum += __shfl_xor(sum, 16);
  sum += __shfl_xor(sum, 32);
  if (lk == 0) sm.redsum[16 * i + lq][sl] = sum;
  asm volatile("s_waitcnt lgkmcnt(0)" ::: "memory");
  __builtin_amdgcn_s_barrier();
  float inv;
  { const float* rp = sm.redsum[16 * i + lq];
    inv = 1.0f / (rp[0] + rp[1] + rp[2] + rp[3]); }
  if (lk == 0 && sl == 0) sm.invl[16 * i + lq] = inv;

  // ---- pack P (unnormalized e) to fp16 pairs; sacc dead after ----
  uint32_t pk[12][2];
  #pragma unroll
  for (int c = 0; c < 12; ++c) {
    H2U a0, a1;
    a0.h[0] = (_Float16)sacc[c][0]; a0.h[1] = (_Float16)sacc[c][1];
    a1.h[0] = (_Float16)sacc[c][2]; a1.h[1] = (_Float16)sacc[c][3];
    pk[c][0] = a0.u; pk[c][1] = a1.u;
  }

  // ---- PV over 6 staged V-tiles; LDS P-exchange (wave-private) ----
  f32x4 oacc[6] = {};
  const int srcA = lq + 16 * (2 * (lk & 1));
  const int srcB = srcA + 16;
  #pragma unroll
  for (int v = 0; v < 6; ++v) {
    if (v < 5) { asm volatile("s_waitcnt vmcnt(3)" ::: "memory"); }
    else       { asm volatile("s_waitcnt vmcnt(0)" ::: "memory"); }
    __builtin_amdgcn_s_barrier();
    uint4 w = make_uint4(pk[2 * v][0], pk[2 * v][1], pk[2 * v + 1][0], pk[2 * v + 1][1]);
    *(uint4*)&sm.pexch[wv][l][0] = w;
    asm volatile("s_waitcnt lgkmcnt(0)" ::: "memory");
    __builtin_amdgcn_sched_barrier(0);
    uint2 dA = *(const uint2*)((const char*)&sm.pexch[wv][srcA][0] + (lk >> 1) * 8);
    uint2 dB = *(const uint2*)((const char*)&sm.pexch[wv][srcB][0] + (lk >> 1) * 8);
    uint4 pad4 = make_uint4(dA.x, dA.y, dB.x, dB.y);
    f16x8 pa = __builtin_bit_cast(f16x8, pad4);

    const char* bufp = sm.stage[v & 1];
    #pragma unroll
    for (int db = 0; db < 6; ++db) {
      int row = db * 16 + lq;
      int cc = 4 * sl + lk;
      int cp = cc ^ (row & 15);
      f16x8 bv = *(const f16x8*)(bufp + row * 256 + cp * 16);
      oacc[db] = __builtin_amdgcn_mfma_f32_16x16x32_f16(pa, bv, oacc[db], 0, 0, 0);
    }
    asm volatile("s_waitcnt lgkmcnt(0)" ::: "memory");
    __builtin_amdgcn_s_barrier();
    if (v < 4) stage(v + 8);      // V2..V5
  }

  // ---- cross-wave O reduce (ored unions with stage; XOR-swizzled cols) ----
  #pragma unroll
  for (int db = 0; db < 6; ++db)
    #pragma unroll
    for (int r = 0; r < 4; ++r) {
      int row = 16 * i + lk * 4 + r;
      sm.ored[sl][row][(db * 16 + lq) ^ (row & 12)] = oacc[db][r];
    }
  asm volatile("s_waitcnt lgkmcnt(0)" ::: "memory");
  __builtin_amdgcn_s_barrier();

  // ---- AO write (reads ored) ----
  {
    int qq = tid >> 4, dc = tid & 15;
    int qglob = q0 + qq;
    if (dc < 12 && qglob < S_) {
      int d0 = dc * 6;
      float iv = sm.invl[qq];
      _Float16* ap = AO + ((size_t)(b * S_ + qglob)) * E_ + h * D_ + d0;
      #pragma unroll
      for (int e = 0; e < 6; ++e) {
        int col = (d0 + e) ^ (qq & 12);
        float v = sm.ored[0][qq][col] + sm.ored[1][qq][col]
                + sm.ored[2][qq][col] + sm.ored[3][qq][col];
        ap[e] = (_Float16)(v * iv);
      }
    }
  }
  asm volatile("s_waitcnt lgkmcnt(0)" ::: "memory");  // drain ored reads
  __builtin_amdgcn_s_barrier();   // all ored reads done before P spill reuses area

  // ---- P spill: fp16 [32][768], XOR-swizzled 16B units (2-way banks) ----
  {
    int row = 16 * i + lq;
    char* base = (char*)sm.p16 + row * 1536;
    #pragma unroll
    for (int c = 0; c < 12; ++c) {
      int cb = 8 * (c >> 1) + 2 * sl + (c & 1);
      int off = cb * 32 + 8 * lk;
      int swz = off ^ ((row & 7) << 4);
      *(uint2*)(base + swz) = make_uint2(pk[c][0], pk[c][1]);
    }
  }
  asm volatile("s_waitcnt lgkmcnt(0)" ::: "memory");
  __builtin_amdgcn_s_barrier();

  // ---- scores sweep: one WAVE per row, 1KB-contiguous NT stores ----
  {
    #pragma unroll
    for (int rr = 0; rr < 4; ++rr) {
      int row = wv * 4 + rr;           // 0..31
      int qg  = q0 + row;
      if (qg < S_) {
        float ivr = sm.invl[row];
        float* srow = scores + (size_t)bh * S_ * S_ + (size_t)qg * S_;
        const char* base = (const char*)sm.p16 + row * 1536;
        #pragma unroll
        for (int u = 0; u < 3; ++u) {
          int off = u * 512 + 8 * l;   // fp16 bytes
          int swz = off ^ ((row & 7) << 4);
          f16x4 pv4 = *(const f16x4*)(base + swz);
          int k0 = u * 256 + 4 * l;    // float col
          f32x4 vv;
          vv[0] = (float)pv4[0] * ivr; vv[1] = (float)pv4[1] * ivr;
          vv[2] = (float)pv4[2] * ivr; vv[3] = (float)pv4[3] * ivr;
          if (k0 + 3 <= 728)
            __builtin_nontemporal_store(vv, (f32x4*)(srow + k0));
          else if (k0 == 728)
            __builtin_nontemporal_store(vv[0], srow + 728);
        }
      }
    }
  }
}

// ---------------- host launch ----------------
extern "C" void kernel_launch(void* const* d_in, const int* in_sizes, int n_in,
                              void* d_out, int out_size, void* d_ws, size_t ws_size,
                              hipStream_t stream)
{
  const float* hidden = (const float*)d_in[0];
  const float* qkv_w  = (const float*)d_in[1];
  const float* qkv_b  = (const float*)d_in[2];
  const float* out_w  = (const float*)d_in[3];
  const float* out_b  = (const float*)d_in[4];
  float* out    = (float*)d_out;
  float* scores = out + (size_t)M1_ * E_;

  char* ws = (char*)d_ws;
  const size_t szA1 = (size_t)MPAD_ * 1152 * 2;
  const size_t szWq = (size_t)3456 * 1152 * 2;
  const size_t szWo = (size_t)1152 * 1152 * 2;
  const size_t szQ  = (size_t)512 * SQ_ * DP_ * 2;
  const size_t szK  = (size_t)512 * SK_ * DP_ * 2;
  const size_t szV  = (size_t)512 * VR_ * 768 * 2;
  const size_t offA1 = 0;
  const size_t offWq = offA1 + szA1;
  const size_t offWo = offWq + szWq;
  const size_t offQ  = offWo + szWo;
  const size_t offK  = offQ  + szQ;
  const size_t offVt = offK  + szK;
  const size_t need  = offVt + szV;          // ~275 MiB
  if (ws_size < need) return;

  _Float16* A1  = (_Float16*)(ws + offA1);
  _Float16* Wq  = (_Float16*)(ws + offWq);
  _Float16* Wo  = (_Float16*)(ws + offWo);
  _Float16* Qp  = (_Float16*)(ws + offQ);
  _Float16* Kp  = (_Float16*)(ws + offK);
  _Float16* Vtp = (_Float16*)(ws + offVt);
  _Float16* AO  = A1;   // reuse A1 (dead after GEMM1)

  // cvt + targeted pad zeroing (replaces 216MB of memsets with ~25MB)
  cvt_all<<<2048, 256, 0, stream>>>(hidden, qkv_w, out_w, A1, Wq, Wo, Qp, Kp, Vtp);

  gemm_f16<0><<<5376, 256, 0, stream>>>(A1, Wq, qkv_b, Qp, Kp, Vtp, nullptr);
  attn_k<<<11776, 512, 0, stream>>>(Qp, Kp, Vtp, scores, AO);
  gemm_f16<1><<<dim3(183, 9), 256, 0, stream>>>(AO, Wo, out_b, nullptr, nullptr, nullptr, out);
}

// Round 20
// 1109.302 us; speedup vs baseline: 1.0783x; 1.0001x over previous
//
#include <hip/hip_runtime.h>

// ---------------- problem constants ----------------
#define B_    32
#define S_    729
#define E_    1152
#define H_    16
#define D_    72
#define M1_   23328      // B_*S_
#define MPAD_ 23424      // 183*128
#define SQ_   736        // Q rows padded (23*32)
#define SK_   768        // K rows padded (6*128)
#define DP_   96         // head dim padded
#define VR_   96         // V^T rows (d padded)
#define SCALE_ 0.11785113019775793f  // 72^-0.5

typedef __attribute__((ext_vector_type(8))) _Float16 f16x8;
typedef __attribute__((ext_vector_type(4))) _Float16 f16x4;
typedef __attribute__((ext_vector_type(4))) float    f32x4;

#define GLDS16(g, l) __builtin_amdgcn_global_load_lds(                      \
    (__attribute__((address_space(1))) void*)(g),                           \
    (__attribute__((address_space(3))) void*)(l), 16, 0, 0)

union H2U { _Float16 h[2]; uint32_t u; };

// ------- fp32 -> fp16 convert (3 tensors) + targeted pad zeroing --------
// Pads that MUST be zero (0*NaN=NaN in MFMA k-sums):
//   Qp d-pad [all 736 rows][72..95]  (QK d-sum; either side NaN survives)
//   Kp d-pad [all 768 rows][72..95]  (QK d-sum)
//   Vtp s-pad [d<72][729..767]       (PV k-sum vs P=0)
// All other garbage regions are row/col-isolated into discarded outputs.
#define N4H  6718464   // (M1_*E_)/4
#define N4W1 995328    // (3456*1152)/4
#define N4W2 331776    // (1152*1152)/4
#define NQC  (512 * 736 * 3)   // Qp pad chunks (16B each)
#define NKC  (512 * 768 * 3)   // Kp pad chunks
#define NVR  (512 * 72)        // Vtp pad rows (39 shorts each)
__global__ void cvt_all(const float* __restrict__ hid, const float* __restrict__ w1,
                        const float* __restrict__ w2, _Float16* __restrict__ o1,
                        _Float16* __restrict__ o2, _Float16* __restrict__ o3,
                        _Float16* __restrict__ Qp, _Float16* __restrict__ Kp,
                        _Float16* __restrict__ Vtp) {
  const int stride = gridDim.x * blockDim.x;
  const int tid0 = blockIdx.x * blockDim.x + threadIdx.x;
  const uint4 z4 = make_uint4(0, 0, 0, 0);
  // pad zeroing (small)
  for (int idx = tid0; idx < NQC; idx += stride) {
    int row = idx / 3, c = idx - row * 3;
    *(uint4*)((char*)Qp + (size_t)row * 192 + 144 + c * 16) = z4;
  }
  for (int idx = tid0; idx < NKC; idx += stride) {
    int row = idx / 3, c = idx - row * 3;
    *(uint4*)((char*)Kp + (size_t)row * 192 + 144 + c * 16) = z4;
  }
  for (int idx = tid0; idx < NVR; idx += stride) {
    _Float16* p = Vtp + (size_t)idx * 768 + 729;
    #pragma unroll
    for (int s = 0; s < 39; ++s) p[s] = (_Float16)0.0f;
  }
  // fp32 -> fp16 streams (read-once/write-once: non-temporal, ext-vector types)
  for (int i = tid0; i < N4H + N4W1 + N4W2; i += stride) {
    const float* s; _Float16* d; int j;
    if (i < N4H)             { s = hid; d = o1; j = i; }
    else if (i < N4H + N4W1) { s = w1;  d = o2; j = i - N4H; }
    else                     { s = w2;  d = o3; j = i - N4H - N4W1; }
    f32x4 v = __builtin_nontemporal_load((const f32x4*)(s + (size_t)j * 4));
    f16x4 o;
    o[0] = (_Float16)v[0]; o[1] = (_Float16)v[1];
    o[2] = (_Float16)v[2]; o[3] = (_Float16)v[3];
    __builtin_nontemporal_store(o, (f16x4*)(d + (size_t)j * 4));
  }
}

// ---------------- 128x128 fp16 MFMA GEMM (m97 structure) ----------------
// MODE 0: XCD-slab remap (neutral but harmless; bijection verified).
template<int MODE>
__global__ __launch_bounds__(256)
void gemm_f16(const _Float16* __restrict__ A, const _Float16* __restrict__ W,
              const float* __restrict__ bias,
              _Float16* __restrict__ Qp, _Float16* __restrict__ Kp,
              _Float16* __restrict__ Vtp, float* __restrict__ Cout)
{
  int mb, nb;
  if (MODE == 0) {
    const int xcd  = blockIdx.x & 7;
    const int slot = blockIdx.x >> 3;      // 0..671
    const int st   = slot >> 4;            // 0..41
    const int w    = slot & 15;
    const int stm  = st % 6, stn = st / 6; // 6 m-supertiles x 7 n-supertiles
    const int mloc = stm * 4 + (w & 3);
    nb = stn * 4 + (w >> 2);
    const int stripe = (xcd < 7) ? 23 : 22;
    if (mloc >= stripe || nb >= 27) return;   // block-uniform early-out
    mb = (xcd < 7 ? xcd * 23 : 161) + mloc;
  } else {
    mb = blockIdx.x; nb = blockIdx.y;
  }

  __shared__ _Float16 As[128 * 64];
  __shared__ _Float16 Bs[128 * 64];
  const int tid = threadIdx.x;
  const int l  = tid & 63;
  const int wv = tid >> 6;
  const int lq = l & 15, lk = l >> 4;
  const int m0 = mb * 128;
  const int n0 = nb * 128;
  const int wm = (wv & 1) * 64, wn = (wv >> 1) * 64;
  const int srow = l >> 3;
  const int scol = (l & 7) * 8;

  f32x4 acc[4][4] = {};

  for (int k0 = 0; k0 < 1152; k0 += 64) {
    #pragma unroll
    for (int q = 0; q < 4; ++q) {
      int chunk = wv * 4 + q;
      int row = chunk * 8 + srow;
      GLDS16(A + (size_t)(m0 + row) * 1152 + k0 + scol, &As[chunk * 512 + l * 8]);
      GLDS16(W + (size_t)(n0 + row) * 1152 + k0 + scol, &Bs[chunk * 512 + l * 8]);
    }
    __syncthreads();
    #pragma unroll
    for (int kk = 0; kk < 64; kk += 32) {
      f16x8 a[4], b[4];
      #pragma unroll
      for (int i = 0; i < 4; ++i)
        a[i] = *(const f16x8*)&As[(wm + 16 * i + lq) * 64 + kk + lk * 8];
      #pragma unroll
      for (int j = 0; j < 4; ++j)
        b[j] = *(const f16x8*)&Bs[(wn + 16 * j + lq) * 64 + kk + lk * 8];
      #pragma unroll
      for (int i = 0; i < 4; ++i)
        #pragma unroll
        for (int j = 0; j < 4; ++j)
          acc[i][j] = __builtin_amdgcn_mfma_f32_16x16x32_f16(a[i], b[j], acc[i][j], 0, 0, 0);
    }
    __syncthreads();
  }

  #pragma unroll
  for (int i = 0; i < 4; ++i) {
    #pragma unroll
    for (int j = 0; j < 4; ++j) {
      int n = n0 + wn + 16 * j + lq;
      float bn = bias[n];
      #pragma unroll
      for (int r = 0; r < 4; ++r) {
        int m = m0 + wm + 16 * i + lk * 4 + r;
        if (m >= M1_) continue;
        float v = acc[i][j][r] + bn;
        if (MODE == 0) {
          unsigned um = (unsigned)m;
          unsigned bq = um / 729u, s = um - bq * 729u;
          unsigned un = (unsigned)n;
          unsigned which = un / 1152u, e = un - which * 1152u;
          unsigned h = e / 72u, d = e - h * 72u;
          unsigned bh = bq * 16u + h;
          if (which == 0) {
            Qp[((size_t)bh * SQ_ + s) * DP_ + d] = (_Float16)(v * SCALE_);
          } else if (which == 1) {
            Kp[((size_t)bh * SK_ + s) * DP_ + d] = (_Float16)v;
          } else {
            Vtp[((size_t)bh * VR_ + d) * 768 + s] = (_Float16)v;
          }
        } else {
          Cout[(size_t)m * 1152 + n] = v;
        }
      }
    }
  }
}

// ---------------- fused attention (v13/v17, best validated) ----------------
// 512 thr (8 waves); one (bh, 32-q tile). XCD-pinned. 12-tile async pipeline
// (6 K + 6 V), counted vmcnt(3). LDS pexch. NT wave-per-row scores sweep.
struct AttnSmem {
  union {
    char     stage[2][24576];    // K tile [128][192B] / V tile [96][256B]
    float    ored[4][32][96];    // 48KB O-reduce (after PV)
    _Float16 p16[32][768];       // 48KB P spill (after AO write)
  };
  uint32_t pexch[8][64][4];      // per-wave P exchange, 8KB
  float redmax[32][4];
  float redsum[32][4];
  float invl[32];
};

__global__ __launch_bounds__(512, 4)
void attn_k(const _Float16* __restrict__ Q, const _Float16* __restrict__ K,
            const _Float16* __restrict__ Vt, float* __restrict__ scores,
            _Float16* __restrict__ AO)
{
  __shared__ AttnSmem sm;
  const int tid = threadIdx.x;
  const int l   = tid & 63;
  const int wv  = tid >> 6;
  const int lq  = l & 15, lk = l >> 4;
  const int i   = wv >> 2;
  const int sl  = wv & 3;
  // XCD-pinned decode: phys block p -> xcd = p%8; head bh = hl*8+xcd
  const int p    = blockIdx.x;
  const int xcd  = p & 7;
  const int slot = p >> 3;
  const int hl   = slot / 23;
  const int qt   = slot - hl * 23;
  const int bh   = hl * 8 + xcd;
  const int q0   = qt * 32;
  const int b    = bh >> 4, h = bh & 15;

  const _Float16* Qb = Q  + (size_t)bh * SQ_ * DP_;
  const _Float16* Kb = K  + (size_t)bh * SK_ * DP_;
  const _Float16* Vb = Vt + (size_t)bh * VR_ * 768;

  // tiles 0..5 = K tiles, 6..11 = V tiles; buffer = idx&1
  auto stage = [&](int idx) {
    char* buf = sm.stage[idx & 1];
    if (idx < 6) {
      #pragma unroll
      for (int it = 0; it < 3; ++it) {
        int s = it * 512 + tid;                 // 1536 chunks of 16B
        int row = s / 12, cp = s - row * 12;
        int cc = (cp < 8) ? (cp ^ (row & 7)) : (8 + ((cp & 3) ^ ((row >> 1) & 3)));
        GLDS16(Kb + (size_t)(idx * 128 + row) * DP_ + cc * 8, buf + s * 16);
      }
    } else {
      #pragma unroll
      for (int it = 0; it < 3; ++it) {
        int s = it * 512 + tid;
        int row = s >> 4, cp = s & 15;
        int cc = cp ^ (row & 15);
        GLDS16(Vb + (size_t)row * 768 + (idx - 6) * 128 + cc * 8, buf + s * 16);
      }
    }
  };

  // ---- prologue: 2 K-tiles in flight + Q frags ----
  stage(0);
  stage(1);
  f16x8 aq[3];
  {
    const _Float16* qp = Qb + (size_t)(q0 + 16 * i + lq) * DP_ + lk * 8;
    aq[0] = *(const f16x8*)(qp);
    aq[1] = *(const f16x8*)(qp + 32);
    aq[2] = *(const f16x8*)(qp + 64);
  }
  asm volatile("s_waitcnt vmcnt(0)" ::: "memory");
  __builtin_amdgcn_s_barrier();

  // ---- QK^T over 6 staged K-tiles ----
  f32x4 sacc[12] = {};
  #pragma unroll
  for (int t = 0; t < 6; ++t) {
    asm volatile("s_waitcnt vmcnt(3)" ::: "memory");
    __builtin_amdgcn_s_barrier();
    const char* bufp = sm.stage[t & 1];
    #pragma unroll
    for (int lcb = 0; lcb < 2; ++lcb) {
      int row = (2 * sl + lcb) * 16 + lq;
      #pragma unroll
      for (int t3 = 0; t3 < 3; ++t3) {
        int cc = 4 * t3 + lk;
        int cp = (cc < 8) ? (cc ^ (row & 7)) : (8 + ((cc & 3) ^ ((row >> 1) & 3)));
        f16x8 ka = *(const f16x8*)(bufp + row * 192 + cp * 16);
        sacc[2 * t + lcb] = __builtin_amdgcn_mfma_f32_16x16x32_f16(ka, aq[t3], sacc[2 * t + lcb], 0, 0, 0);
      }
    }
    asm volatile("s_waitcnt lgkmcnt(0)" ::: "memory");
    __builtin_amdgcn_s_barrier();
    stage(t + 2);                 // t+2: K2..K5 then V0,V1
  }

  // ---- mask invalid k (cb >= 45 only at c=10,11) ----
  #pragma unroll
  for (int c = 10; c < 12; ++c) {
    int kbase = (40 + 2 * sl + (c & 1)) * 16 + 4 * lk;
    #pragma unroll
    for (int r = 0; r < 4; ++r)
      if (kbase + r > 728) sacc[c][r] = -1e30f;
  }

  // ---- row max (V0/V1 loads in flight underneath) ----
  float m = -1e30f;
  #pragma unroll
  for (int c = 0; c < 12; ++c)
    #pragma unroll
    for (int r = 0; r < 4; ++r) m = fmaxf(m, sacc[c][r]);
  m = fmaxf(m, __shfl_xor(m, 16));
  m = fmaxf(m, __shfl_xor(m, 32));
  if (lk == 0) sm.redmax[16 * i + lq][sl] = m;
  asm volatile("s_waitcnt lgkmcnt(0)" ::: "memory");
  __builtin_amdgcn_s_barrier();
  float gm;
  { const float* rp = sm.redmax[16 * i + lq];
    gm = fmaxf(fmaxf(rp[0], rp[1]), fmaxf(rp[2], rp[3])); }

  // ---- exp + row sum ----
  float sum = 0.f;
  #pragma unroll
  for (int c = 0; c < 12; ++c)
    #pragma unroll
    for (int r = 0; r < 4; ++r) {
      float e = __expf(sacc[c][r] - gm);
      sacc[c][r] = e;
      sum += e;
    }
  sum += __shfl_xor(sum, 16);
  sum += __shfl_xor(sum, 32);
  if (lk == 0) sm.redsum[16 * i + lq][sl] = sum;
  asm volatile("s_waitcnt lgkmcnt(0)" ::: "memory");
  __builtin_amdgcn_s_barrier();
  float inv;
  { const float* rp = sm.redsum[16 * i + lq];
    inv = 1.0f / (rp[0] + rp[1] + rp[2] + rp[3]); }
  if (lk == 0 && sl == 0) sm.invl[16 * i + lq] = inv;

  // ---- pack P (unnormalized e) to fp16 pairs; sacc dead after ----
  uint32_t pk[12][2];
  #pragma unroll
  for (int c = 0; c < 12; ++c) {
    H2U a0, a1;
    a0.h[0] = (_Float16)sacc[c][0]; a0.h[1] = (_Float16)sacc[c][1];
    a1.h[0] = (_Float16)sacc[c][2]; a1.h[1] = (_Float16)sacc[c][3];
    pk[c][0] = a0.u; pk[c][1] = a1.u;
  }

  // ---- PV over 6 staged V-tiles; LDS P-exchange (wave-private) ----
  f32x4 oacc[6] = {};
  const int srcA = lq + 16 * (2 * (lk & 1));
  const int srcB = srcA + 16;
  #pragma unroll
  for (int v = 0; v < 6; ++v) {
    if (v < 5) { asm volatile("s_waitcnt vmcnt(3)" ::: "memory"); }
    else       { asm volatile("s_waitcnt vmcnt(0)" ::: "memory"); }
    __builtin_amdgcn_s_barrier();
    uint4 w = make_uint4(pk[2 * v][0], pk[2 * v][1], pk[2 * v + 1][0], pk[2 * v + 1][1]);
    *(uint4*)&sm.pexch[wv][l][0] = w;
    asm volatile("s_waitcnt lgkmcnt(0)" ::: "memory");
    __builtin_amdgcn_sched_barrier(0);
    uint2 dA = *(const uint2*)((const char*)&sm.pexch[wv][srcA][0] + (lk >> 1) * 8);
    uint2 dB = *(const uint2*)((const char*)&sm.pexch[wv][srcB][0] + (lk >> 1) * 8);
    uint4 pad4 = make_uint4(dA.x, dA.y, dB.x, dB.y);
    f16x8 pa = __builtin_bit_cast(f16x8, pad4);

    const char* bufp = sm.stage[v & 1];
    #pragma unroll
    for (int db = 0; db < 6; ++db) {
      int row = db * 16 + lq;
      int cc = 4 * sl + lk;
      int cp = cc ^ (row & 15);
      f16x8 bv = *(const f16x8*)(bufp + row * 256 + cp * 16);
      oacc[db] = __builtin_amdgcn_mfma_f32_16x16x32_f16(pa, bv, oacc[db], 0, 0, 0);
    }
    asm volatile("s_waitcnt lgkmcnt(0)" ::: "memory");
    __builtin_amdgcn_s_barrier();
    if (v < 4) stage(v + 8);      // V2..V5
  }

  // ---- cross-wave O reduce (ored unions with stage; XOR-swizzled cols) ----
  #pragma unroll
  for (int db = 0; db < 6; ++db)
    #pragma unroll
    for (int r = 0; r < 4; ++r) {
      int row = 16 * i + lk * 4 + r;
      sm.ored[sl][row][(db * 16 + lq) ^ (row & 12)] = oacc[db][r];
    }
  asm volatile("s_waitcnt lgkmcnt(0)" ::: "memory");
  __builtin_amdgcn_s_barrier();

  // ---- AO write (reads ored) ----
  {
    int qq = tid >> 4, dc = tid & 15;
    int qglob = q0 + qq;
    if (dc < 12 && qglob < S_) {
      int d0 = dc * 6;
      float iv = sm.invl[qq];
      _Float16* ap = AO + ((size_t)(b * S_ + qglob)) * E_ + h * D_ + d0;
      #pragma unroll
      for (int e = 0; e < 6; ++e) {
        int col = (d0 + e) ^ (qq & 12);
        float v = sm.ored[0][qq][col] + sm.ored[1][qq][col]
                + sm.ored[2][qq][col] + sm.ored[3][qq][col];
        ap[e] = (_Float16)(v * iv);
      }
    }
  }
  asm volatile("s_waitcnt lgkmcnt(0)" ::: "memory");  // drain ored reads
  __builtin_amdgcn_s_barrier();   // all ored reads done before P spill reuses area

  // ---- P spill: fp16 [32][768], XOR-swizzled 16B units (2-way banks) ----
  {
    int row = 16 * i + lq;
    char* base = (char*)sm.p16 + row * 1536;
    #pragma unroll
    for (int c = 0; c < 12; ++c) {
      int cb = 8 * (c >> 1) + 2 * sl + (c & 1);
      int off = cb * 32 + 8 * lk;
      int swz = off ^ ((row & 7) << 4);
      *(uint2*)(base + swz) = make_uint2(pk[c][0], pk[c][1]);
    }
  }
  asm volatile("s_waitcnt lgkmcnt(0)" ::: "memory");
  __builtin_amdgcn_s_barrier();

  // ---- scores sweep: one WAVE per row, 1KB-contiguous NT stores ----
  {
    #pragma unroll
    for (int rr = 0; rr < 4; ++rr) {
      int row = wv * 4 + rr;           // 0..31
      int qg  = q0 + row;
      if (qg < S_) {
        float ivr = sm.invl[row];
        float* srow = scores + (size_t)bh * S_ * S_ + (size_t)qg * S_;
        const char* base = (const char*)sm.p16 + row * 1536;
        #pragma unroll
        for (int u = 0; u < 3; ++u) {
          int off = u * 512 + 8 * l;   // fp16 bytes
          int swz = off ^ ((row & 7) << 4);
          f16x4 pv4 = *(const f16x4*)(base + swz);
          int k0 = u * 256 + 4 * l;    // float col
          f32x4 vv;
          vv[0] = (float)pv4[0] * ivr; vv[1] = (float)pv4[1] * ivr;
          vv[2] = (float)pv4[2] * ivr; vv[3] = (float)pv4[3] * ivr;
          if (k0 + 3 <= 728)
            __builtin_nontemporal_store(vv, (f32x4*)(srow + k0));
          else if (k0 == 728)
            __builtin_nontemporal_store(vv[0], srow + 728);
        }
      }
    }
  }
}

// ---------------- host launch ----------------
extern "C" void kernel_launch(void* const* d_in, const int* in_sizes, int n_in,
                              void* d_out, int out_size, void* d_ws, size_t ws_size,
                              hipStream_t stream)
{
  const float* hidden = (const float*)d_in[0];
  const float* qkv_w  = (const float*)d_in[1];
  const float* qkv_b  = (const float*)d_in[2];
  const float* out_w  = (const float*)d_in[3];
  const float* out_b  = (const float*)d_in[4];
  float* out    = (float*)d_out;
  float* scores = out + (size_t)M1_ * E_;

  char* ws = (char*)d_ws;
  const size_t szA1 = (size_t)MPAD_ * 1152 * 2;
  const size_t szWq = (size_t)3456 * 1152 * 2;
  const size_t szWo = (size_t)1152 * 1152 * 2;
  const size_t szQ  = (size_t)512 * SQ_ * DP_ * 2;
  const size_t szK  = (size_t)512 * SK_ * DP_ * 2;
  const size_t szV  = (size_t)512 * VR_ * 768 * 2;
  const size_t offA1 = 0;
  const size_t offWq = offA1 + szA1;
  const size_t offWo = offWq + szWq;
  const size_t offQ  = offWo + szWo;
  const size_t offK  = offQ  + szQ;
  const size_t offVt = offK  + szK;
  const size_t need  = offVt + szV;          // ~275 MiB
  if (ws_size < need) return;

  _Float16* A1  = (_Float16*)(ws + offA1);
  _Float16* Wq  = (_Float16*)(ws + offWq);
  _Float16* Wo  = (_Float16*)(ws + offWo);
  _Float16* Qp  = (_Float16*)(ws + offQ);
  _Float16* Kp  = (_Float16*)(ws + offK);
  _Float16* Vtp = (_Float16*)(ws + offVt);
  _Float16* AO  = A1;   // reuse A1 (dead after GEMM1)

  // cvt + targeted pad zeroing (replaces 216MB of memsets with ~25MB)
  cvt_all<<<2048, 256, 0, stream>>>(hidden, qkv_w, out_w, A1, Wq, Wo, Qp, Kp, Vtp);

  gemm_f16<0><<<5376, 256, 0, stream>>>(A1, Wq, qkv_b, Qp, Kp, Vtp, nullptr);
  attn_k<<<11776, 512, 0, stream>>>(Qp, Kp, Vtp, scores, AO);
  gemm_f16<1><<<dim3(183, 9), 256, 0, stream>>>(AO, Wo, out_b, nullptr, nullptr, nullptr, out);
}